// Round 3
// baseline (126.567 us; speedup 1.0000x reference)
//
#include <hip/hip_runtime.h>
#include <hip/hip_cooperative_groups.h>

namespace cg = cooperative_groups;

// out[b,n] = relu( sum_d x[b, idx[n,d]] * w[n,d] )
//   x: (B=256, N=16384) f32, w: (N,32) f32, idx: (N,32) i32, out: (B,N) f32
//
// R12: fuse prep into gather as ONE cooperative kernel (256 blocks x 1024,
// 1 block/CU at 128 KiB LDS -> co-residency guaranteed by the coop API).
// Phase 0: each block packs the pw4 slice for its own 64-n range (same
//   LDS-transpose + pk16 math as the old prep kernel, bit-identical).
// Phase 1: stage the x quad-image into LDS (identical to R11).
// Phase 2: grid.sync() -- makes all blocks' pw4 writes visible.
// Phase 3: R11 hot loop unchanged (uint4 stream ping-pong, ds_read_b64
//   gathers, pk_fma, NT out stores).
// This removes the separate prep dispatch + one in-graph dispatch gap
// (~6-8 us) at the cost of one grid sync (~2-3 us). Numerics identical.
// Fallback: if the cooperative enqueue is rejected (e.g. capture), launch
// the R11 two-kernel path instead.

#define NB   16384
#define DEG  32

typedef __fp16 hp2 __attribute__((ext_vector_type(2)));  // cvt_pkrtz result type

__device__ __forceinline__ unsigned pk16(float a, float b) {
    return __builtin_bit_cast(unsigned, (hp2)__builtin_amdgcn_cvt_pkrtz(a, b));
}

// ---------------- shared hot-loop machinery (R11) ----------------

// Load all 8 uint4 streams for column nn into a register buffer.
#define LOADQ(buf, nn)                                                     \
    do {                                                                   \
        const uint4* p_ = pw4 + (nn);                                      \
        _Pragma("unroll") for (int d4_ = 0; d4_ < 8; ++d4_)                \
            buf[d4_] = p_[(size_t)d4_ * NB];                               \
    } while (0)

// Consume one uint4 = two d2-groups: 4 ds_read_b64 + 8 v_pk_fma_f16.
#define ACC2(buf, D4, r01, r23)                                            \
    {                                                                      \
        const unsigned jpA = buf[D4].x;                                    \
        const uint2 gA0 = lds[jpA & 0xffffu];                              \
        const uint2 gA1 = lds[jpA >> 16];                                  \
        const hp2 wA  = __builtin_bit_cast(hp2, buf[D4].y);                \
        const hp2 wAlo = {wA.x, wA.x};                                     \
        const hp2 wAhi = {wA.y, wA.y};                                     \
        r01 += wAlo * __builtin_bit_cast(hp2, gA0.x);                      \
        r23 += wAlo * __builtin_bit_cast(hp2, gA0.y);                      \
        r01 += wAhi * __builtin_bit_cast(hp2, gA1.x);                      \
        r23 += wAhi * __builtin_bit_cast(hp2, gA1.y);                      \
        const unsigned jpB = buf[D4].z;                                    \
        const uint2 gB0 = lds[jpB & 0xffffu];                              \
        const uint2 gB1 = lds[jpB >> 16];                                  \
        const hp2 wB  = __builtin_bit_cast(hp2, buf[D4].w);                \
        const hp2 wBlo = {wB.x, wB.x};                                     \
        const hp2 wBhi = {wB.y, wB.y};                                     \
        r01 += wBlo * __builtin_bit_cast(hp2, gB0.x);                      \
        r23 += wBlo * __builtin_bit_cast(hp2, gB0.y);                      \
        r01 += wBhi * __builtin_bit_cast(hp2, gB1.x);                      \
        r23 += wBhi * __builtin_bit_cast(hp2, gB1.y);                      \
    }

#define STEP(CUR, NXT, I, PF)                                              \
    {                                                                      \
        const int n = n0 + t + 1024 * (I);                                 \
        if (PF) LOADQ(NXT, n + 1024);                                      \
        hp2 a01 = {0, 0}, a23 = {0, 0}, c01 = {0, 0}, c23 = {0, 0};        \
        ACC2(CUR, 0, a01, a23)                                             \
        ACC2(CUR, 1, a01, a23)                                             \
        ACC2(CUR, 2, a01, a23)                                             \
        ACC2(CUR, 3, a01, a23)                                             \
        ACC2(CUR, 4, c01, c23)                                             \
        ACC2(CUR, 5, c01, c23)                                             \
        ACC2(CUR, 6, c01, c23)                                             \
        ACC2(CUR, 7, c01, c23)                                             \
        const hp2 s01 = a01 + c01;                                         \
        const hp2 s23 = a23 + c23;                                         \
        __builtin_nontemporal_store(fmaxf((float)s01.x, 0.f),              \
                                    &out[(size_t)(b0 + 0) * NB + n]);      \
        __builtin_nontemporal_store(fmaxf((float)s01.y, 0.f),              \
                                    &out[(size_t)(b0 + 1) * NB + n]);      \
        __builtin_nontemporal_store(fmaxf((float)s23.x, 0.f),              \
                                    &out[(size_t)(b0 + 2) * NB + n]);      \
        __builtin_nontemporal_store(fmaxf((float)s23.y, 0.f),              \
                                    &out[(size_t)(b0 + 3) * NB + n]);      \
    }

// Stage the quad j-image (batches 4q..4q+3, h2-packed) into LDS.
#define STAGE_X_IMAGE()                                                    \
    {                                                                      \
        const float* xr0 = x + (size_t)(4 * q) * NB;                       \
        const float* xr1 = xr0 + NB;                                       \
        const float* xr2 = xr1 + NB;                                       \
        const float* xr3 = xr2 + NB;                                       \
        _Pragma("unroll") for (int p = 0; p < 4; ++p) {                    \
            const int j = 4 * (t + 1024 * p);                              \
            const float4 r0 = *(const float4*)&xr0[j];                     \
            const float4 r1 = *(const float4*)&xr1[j];                     \
            const float4 r2 = *(const float4*)&xr2[j];                     \
            const float4 r3 = *(const float4*)&xr3[j];                     \
            uint4 w0, w1;                                                  \
            w0.x = pk16(r0.x, r1.x); w0.y = pk16(r2.x, r3.x);              \
            w0.z = pk16(r0.y, r1.y); w0.w = pk16(r2.y, r3.y);              \
            w1.x = pk16(r0.z, r1.z); w1.y = pk16(r2.z, r3.z);              \
            w1.z = pk16(r0.w, r1.w); w1.w = pk16(r2.w, r3.w);              \
            *(uint4*)&lds[j]     = w0;                                     \
            *(uint4*)&lds[j + 2] = w1;                                     \
        }                                                                  \
    }

// ---------------- fused cooperative kernel ----------------

__global__ __launch_bounds__(1024, 4) void fused_kernel(
    const float* __restrict__ x, const int* __restrict__ idx,
    const float* __restrict__ w, uint4* __restrict__ pw4,
    float* __restrict__ out) {
    extern __shared__ uint2 lds[];               // 16384 uint2 = 128 KiB
    const int t   = threadIdx.x;
    const int bid = (int)blockIdx.x;
    const int q   = bid & 63;                    // quad 0..63 -> b = 4q..4q+3
    const int n0  = (bid >> 6) * 4096;           // split-major: XCD = q%8

    // Phase 0: pack pw4 for n-range [bid*64, bid*64+64). Same transpose +
    // pk16 math as the old prep kernel; LDS front is a temp (overwritten by
    // the image after the syncthreads).
    {
        int*   idx_s = (int*)lds;                // [64][33]
        float* w_s   = (float*)lds + 64 * 33;    // [64][33]
        const int nb = bid * 64;
        if (t < 512) {
            const int4   v = ((const int4*)(idx + (size_t)nb * DEG))[t];
            const float4 f = ((const float4*)(w  + (size_t)nb * DEG))[t];
            const int nr = t >> 3;               // 0..63
            const int c0 = (t & 7) * 4;          // 0..28
            idx_s[nr * 33 + c0 + 0] = v.x; idx_s[nr * 33 + c0 + 1] = v.y;
            idx_s[nr * 33 + c0 + 2] = v.z; idx_s[nr * 33 + c0 + 3] = v.w;
            w_s[nr * 33 + c0 + 0] = f.x; w_s[nr * 33 + c0 + 1] = f.y;
            w_s[nr * 33 + c0 + 2] = f.z; w_s[nr * 33 + c0 + 3] = f.w;
        }
        __syncthreads();
        if (t < 512) {
            const int np = t & 63;               // coalesced store
            const int d4 = t >> 6;               // 0..7
            const int c  = 4 * d4;
            uint4 o;
            o.x = (unsigned)idx_s[np * 33 + c + 0] |
                  ((unsigned)idx_s[np * 33 + c + 1] << 16);
            o.y = pk16(w_s[np * 33 + c + 0], w_s[np * 33 + c + 1]);
            o.z = (unsigned)idx_s[np * 33 + c + 2] |
                  ((unsigned)idx_s[np * 33 + c + 3] << 16);
            o.w = pk16(w_s[np * 33 + c + 2], w_s[np * 33 + c + 3]);
            pw4[(size_t)d4 * NB + nb + np] = o;
        }
        __syncthreads();                         // temp dead; image may write
    }

    // Phase 1: stage x quad-image (independent of other blocks' pw).
    STAGE_X_IMAGE();

    // Phase 2: all pw4 writes visible device-wide.
    cg::this_grid().sync();

    // Phase 3: hot loop (R11). First LOADQ exposed once (~0.2 us).
    uint4 U[8], V[8];
    LOADQ(U, n0 + t);
    const int b0 = 4 * q;
    STEP(U, V, 0, 1)
    STEP(V, U, 1, 1)
    STEP(U, V, 2, 1)
    STEP(V, U, 3, 0)
}

// ---------------- R11 fallback path (two kernels) ----------------

__global__ __launch_bounds__(256) void prep_pw_kernel(
    const int* __restrict__ idx, const float* __restrict__ w,
    uint4* __restrict__ pw4) {
    __shared__ int   idx_s[64][33];
    __shared__ float w_s[64][33];
    const int t  = threadIdx.x;
    const int nb = (int)blockIdx.x * 64;

    const int4*   src  = (const int4*)(idx + (size_t)nb * DEG);
    const float4* srcw = (const float4*)(w   + (size_t)nb * DEG);
#pragma unroll
    for (int p = 0; p < 2; ++p) {
        const int e4 = t + 256 * p;
        const int n0 = e4 >> 3;
        const int c0 = (e4 & 7) * 4;
        const int4 v = src[e4];
        idx_s[n0][c0 + 0] = v.x; idx_s[n0][c0 + 1] = v.y;
        idx_s[n0][c0 + 2] = v.z; idx_s[n0][c0 + 3] = v.w;
        const float4 f = srcw[e4];
        w_s[n0][c0 + 0] = f.x; w_s[n0][c0 + 1] = f.y;
        w_s[n0][c0 + 2] = f.z; w_s[n0][c0 + 3] = f.w;
    }
    __syncthreads();

    const int np    = t & 63;
    const int dbase = t >> 6;
#pragma unroll
    for (int k = 0; k < 2; ++k) {
        const int d4 = dbase * 2 + k;
        const int c  = 4 * d4;
        uint4 o;
        o.x = (unsigned)idx_s[np][c + 0] | ((unsigned)idx_s[np][c + 1] << 16);
        o.y = pk16(w_s[np][c + 0], w_s[np][c + 1]);
        o.z = (unsigned)idx_s[np][c + 2] | ((unsigned)idx_s[np][c + 3] << 16);
        o.w = pk16(w_s[np][c + 2], w_s[np][c + 3]);
        pw4[(size_t)d4 * NB + nb + np] = o;
    }
}

__global__ __launch_bounds__(1024, 4) void gather4_kernel(
    const float* __restrict__ x, const uint4* __restrict__ pw4,
    float* __restrict__ out) {
    extern __shared__ uint2 lds[];
    const int t  = threadIdx.x;
    const int q  = (int)blockIdx.x & 63;
    const int n0 = ((int)blockIdx.x >> 6) * 4096;

    STAGE_X_IMAGE();

    uint4 U[8], V[8];
    LOADQ(U, n0 + t);
    __syncthreads();

    const int b0 = 4 * q;
    STEP(U, V, 0, 1)
    STEP(V, U, 1, 1)
    STEP(U, V, 2, 1)
    STEP(V, U, 3, 0)
}

extern "C" void kernel_launch(void* const* d_in, const int* in_sizes, int n_in,
                              void* d_out, int out_size, void* d_ws, size_t ws_size,
                              hipStream_t stream) {
    const float* x   = (const float*)d_in[0];    // (B, N)
    const float* w   = (const float*)d_in[1];    // (N, DEG)
    const int*   idx = (const int*)d_in[2];      // (N, DEG)
    float* out = (float*)d_out;                  // (B, N)
    uint4* pw4 = (uint4*)d_ws;                   // [8][N] uint4 = 2 MiB

    // allow 128 KiB dynamic LDS (idempotent; host-side, capture-safe)
    (void)hipFuncSetAttribute((const void*)fused_kernel,
                              hipFuncAttributeMaxDynamicSharedMemorySize, 131072);
    (void)hipFuncSetAttribute((const void*)gather4_kernel,
                              hipFuncAttributeMaxDynamicSharedMemorySize, 131072);

    void* args[5] = {(void*)&x, (void*)&idx, (void*)&w, (void*)&pw4, (void*)&out};
    hipError_t e = hipLaunchCooperativeKernel((const void*)fused_kernel,
                                              dim3(256), dim3(1024), args,
                                              131072, stream);
    if (e != hipSuccess) {
        // Fallback: R11 two-kernel path.
        (void)hipGetLastError();
        prep_pw_kernel<<<NB / 64, 256, 0, stream>>>(idx, w, pw4);
        gather4_kernel<<<256, 1024, 131072, stream>>>(x, pw4, out);
    }
}

// Round 4
// 83.826 us; speedup vs baseline: 1.5099x; 1.5099x over previous
//
#include <hip/hip_runtime.h>

// out[b,n] = relu( sum_d x[b, idx[n,d]] * w[n,d] )
//   x: (B=256, N=16384) f32, w: (N,32) f32, idx: (N,32) i32, out: (B,N) f32
//
// R13: revert coop fusion (R12 regressed: +20us launch overhead + ~12us
// grid.sync; back to R11 two-kernel path). Counter evidence from R12's
// fused run: LDS only ~38% busy (conflict 5.6us + base 6.8us vs ~33us hot
// loop), VALUBusy 7%, HBM 8% -> hot loop is lgkmcnt-latency-exposed, not
// LDS-throughput-bound. Cause: per-ACC2 drain (4 outstanding ds_reads)
// under the 128-VGPR cap, with 64 VGPRs wasted on the U/V VMEM ping-pong
// that R10/R11 proved worthless (both null).
// Change: single Q buffer (VMEM prefetch dropped), registers spent on LDS
// software pipeline instead: issue 4 gather-groups (16 ds_read_b64) ahead,
// then fma group k while issuing group k+4. Steady-state ~16 outstanding
// LDS reads/wave -> LDS approaches its service floor.
// FP accumulation order identical to R9-R12 (groups 0-3 -> a, 4-7 -> c).

#define NB   16384
#define DEG  32

typedef __fp16 hp2 __attribute__((ext_vector_type(2)));  // cvt_pkrtz result type

__device__ __forceinline__ unsigned pk16(float a, float b) {
    return __builtin_bit_cast(unsigned, (hp2)__builtin_amdgcn_cvt_pkrtz(a, b));
}

// prep: pack (idx,w) rows into 8 coalesced uint4 streams:
//   pw4[d4][n] = { idxpair(2*d4), wpair(2*d4), idxpair(2*d4+1), wpair(2*d4+1) }
__global__ __launch_bounds__(256) void prep_pw_kernel(
    const int* __restrict__ idx, const float* __restrict__ w,
    uint4* __restrict__ pw4) {
    __shared__ int   idx_s[64][33];
    __shared__ float w_s[64][33];
    const int t  = threadIdx.x;
    const int nb = (int)blockIdx.x * 64;

    const int4*   src  = (const int4*)(idx + (size_t)nb * DEG);
    const float4* srcw = (const float4*)(w   + (size_t)nb * DEG);
#pragma unroll
    for (int p = 0; p < 2; ++p) {
        const int e4 = t + 256 * p;              // int4 index 0..511, coalesced
        const int n0 = e4 >> 3;
        const int c0 = (e4 & 7) * 4;
        const int4 v = src[e4];
        idx_s[n0][c0 + 0] = v.x; idx_s[n0][c0 + 1] = v.y;
        idx_s[n0][c0 + 2] = v.z; idx_s[n0][c0 + 3] = v.w;
        const float4 f = srcw[e4];
        w_s[n0][c0 + 0] = f.x; w_s[n0][c0 + 1] = f.y;
        w_s[n0][c0 + 2] = f.z; w_s[n0][c0 + 3] = f.w;
    }
    __syncthreads();

    const int np    = t & 63;
    const int dbase = t >> 6;                    // 0..3
#pragma unroll
    for (int k = 0; k < 2; ++k) {
        const int d4 = dbase * 2 + k;            // 0..7
        const int c  = 4 * d4;                   // first of 4 d-columns
        uint4 o;
        o.x = (unsigned)idx_s[np][c + 0] | ((unsigned)idx_s[np][c + 1] << 16);
        o.y = pk16(w_s[np][c + 0], w_s[np][c + 1]);
        o.z = (unsigned)idx_s[np][c + 2] | ((unsigned)idx_s[np][c + 3] << 16);
        o.w = pk16(w_s[np][c + 2], w_s[np][c + 3]);
        pw4[(size_t)d4 * NB + nb + np] = o;
    }
}

// Load all 8 uint4 streams for column nn into the Q buffer.
#define LOADQ(buf, nn)                                                     \
    do {                                                                   \
        const uint4* p_ = pw4 + (nn);                                      \
        _Pragma("unroll") for (int d4_ = 0; d4_ < 8; ++d4_)                \
            buf[d4_] = p_[(size_t)d4_ * NB];                               \
    } while (0)

// Issue the 4 ds_read_b64 gathers for group K (addresses from Q[K].x/.z).
#define GISSUE(K)                                                          \
    {                                                                      \
        const unsigned jA_ = Q[K].x;                                       \
        g[K][0] = lds[jA_ & 0xffffu];                                      \
        g[K][1] = lds[jA_ >> 16];                                          \
        const unsigned jB_ = Q[K].z;                                       \
        g[K][2] = lds[jB_ & 0xffffu];                                      \
        g[K][3] = lds[jB_ >> 16];                                          \
    }

// Consume group K: 8 v_pk_fma_f16 (order identical to R11's ACC2).
#define GFMA(K, r01, r23)                                                  \
    {                                                                      \
        const hp2 wA_  = __builtin_bit_cast(hp2, Q[K].y);                  \
        const hp2 wAlo = {wA_.x, wA_.x};                                   \
        const hp2 wAhi = {wA_.y, wA_.y};                                   \
        r01 += wAlo * __builtin_bit_cast(hp2, g[K][0].x);                  \
        r23 += wAlo * __builtin_bit_cast(hp2, g[K][0].y);                  \
        r01 += wAhi * __builtin_bit_cast(hp2, g[K][1].x);                  \
        r23 += wAhi * __builtin_bit_cast(hp2, g[K][1].y);                  \
        const hp2 wB_  = __builtin_bit_cast(hp2, Q[K].w);                  \
        const hp2 wBlo = {wB_.x, wB_.x};                                   \
        const hp2 wBhi = {wB_.y, wB_.y};                                   \
        r01 += wBlo * __builtin_bit_cast(hp2, g[K][2].x);                  \
        r23 += wBlo * __builtin_bit_cast(hp2, g[K][2].y);                  \
        r01 += wBhi * __builtin_bit_cast(hp2, g[K][3].x);                  \
        r23 += wBhi * __builtin_bit_cast(hp2, g[K][3].y);                  \
    }

// One column: optional stream load, LDS-pipelined gather+fma, NT stores.
// LDS pipeline: groups 0-3 issued ahead; fma(k) overlaps issue(k+4).
#define STEP(I, LD)                                                        \
    {                                                                      \
        const int n = n0 + t + 1024 * (I);                                 \
        if (LD) LOADQ(Q, n);                                               \
        uint2 g[8][4];                                                     \
        GISSUE(0) GISSUE(1) GISSUE(2) GISSUE(3)                            \
        hp2 a01 = {0, 0}, a23 = {0, 0}, c01 = {0, 0}, c23 = {0, 0};        \
        GFMA(0, a01, a23) GISSUE(4)                                        \
        GFMA(1, a01, a23) GISSUE(5)                                        \
        GFMA(2, a01, a23) GISSUE(6)                                        \
        GFMA(3, a01, a23) GISSUE(7)                                        \
        GFMA(4, c01, c23)                                                  \
        GFMA(5, c01, c23)                                                  \
        GFMA(6, c01, c23)                                                  \
        GFMA(7, c01, c23)                                                  \
        const hp2 s01 = a01 + c01;                                         \
        const hp2 s23 = a23 + c23;                                         \
        __builtin_nontemporal_store(fmaxf((float)s01.x, 0.f),              \
                                    &out[(size_t)(b0 + 0) * NB + n]);      \
        __builtin_nontemporal_store(fmaxf((float)s01.y, 0.f),              \
                                    &out[(size_t)(b0 + 1) * NB + n]);      \
        __builtin_nontemporal_store(fmaxf((float)s23.x, 0.f),              \
                                    &out[(size_t)(b0 + 2) * NB + n]);      \
        __builtin_nontemporal_store(fmaxf((float)s23.y, 0.f),              \
                                    &out[(size_t)(b0 + 3) * NB + n]);      \
    }

__global__ __launch_bounds__(1024, 4) void gather4_kernel(
    const float* __restrict__ x, const uint4* __restrict__ pw4,
    float* __restrict__ out) {
    extern __shared__ uint2 lds[];               // 16384 uint2 = 128 KiB
    const int t  = threadIdx.x;
    const int q  = (int)blockIdx.x & 63;         // quad 0..63 -> b = 4q..4q+3
    const int n0 = ((int)blockIdx.x >> 6) * 4096;  // split-major: XCD = q%8

    // Stage quad j-image straight from x (coalesced float4 per row; rows are
    // L2-hot for 3 of the 4 split-blocks). ds_write_b128 stride-32B: clean.
    const float* xr0 = x + (size_t)(4 * q) * NB;
    const float* xr1 = xr0 + NB;
    const float* xr2 = xr1 + NB;
    const float* xr3 = xr2 + NB;
#pragma unroll
    for (int p = 0; p < 4; ++p) {
        const int j = 4 * (t + 1024 * p);
        const float4 r0 = *(const float4*)&xr0[j];
        const float4 r1 = *(const float4*)&xr1[j];
        const float4 r2 = *(const float4*)&xr2[j];
        const float4 r3 = *(const float4*)&xr3[j];
        uint4 w0, w1;
        w0.x = pk16(r0.x, r1.x); w0.y = pk16(r2.x, r3.x);
        w0.z = pk16(r0.y, r1.y); w0.w = pk16(r2.y, r3.y);
        w1.x = pk16(r0.z, r1.z); w1.y = pk16(r2.z, r3.z);
        w1.z = pk16(r0.w, r1.w); w1.w = pk16(r2.w, r3.w);
        *(uint4*)&lds[j]     = w0;
        *(uint4*)&lds[j + 2] = w1;
    }

    uint4 Q[8];
    // i=0 streams issued before the barrier: latency hides under the
    // staging drain + barrier.
    LOADQ(Q, n0 + t);
    __syncthreads();

    const int b0 = 4 * q;
    STEP(0, 0)
    STEP(1, 1)
    STEP(2, 1)
    STEP(3, 1)
}

extern "C" void kernel_launch(void* const* d_in, const int* in_sizes, int n_in,
                              void* d_out, int out_size, void* d_ws, size_t ws_size,
                              hipStream_t stream) {
    const float* x   = (const float*)d_in[0];    // (B, N)
    const float* w   = (const float*)d_in[1];    // (N, DEG)
    const int*   idx = (const int*)d_in[2];      // (N, DEG)
    float* out = (float*)d_out;                  // (B, N)
    uint4* pw4 = (uint4*)d_ws;                   // [8][N] uint4 = 2 MiB

    // allow 128 KiB dynamic LDS (idempotent; host-side, capture-safe)
    (void)hipFuncSetAttribute((const void*)gather4_kernel,
                              hipFuncAttributeMaxDynamicSharedMemorySize, 131072);

    prep_pw_kernel<<<NB / 64, 256, 0, stream>>>(idx, w, pw4);

    gather4_kernel<<<256, 1024, 131072, stream>>>(x, pw4, out);
}